// Round 15
// baseline (243.089 us; speedup 1.0000x reference)
//
#include <hip/hip_runtime.h>

typedef unsigned short u16;
typedef unsigned int   u32;
typedef __bf16 bf16;
typedef bf16 bf16x8 __attribute__((ext_vector_type(8)));
typedef float f32x4 __attribute__((ext_vector_type(4)));
typedef u32 u32x4 __attribute__((ext_vector_type(4)));

__device__ inline u16 f2bf(float f) {
  union { float f; u32 u; } cv; cv.f = f;
  u32 u = cv.u;
  return (u16)((u + 0x7FFFu + ((u >> 16) & 1u)) >> 16);
}

__device__ __forceinline__ void gld16(const void* g, void* l) {
  __builtin_amdgcn_global_load_lds(
      (const __attribute__((address_space(1))) void*)g,
      (__attribute__((address_space(3))) void*)l, 16, 0, 0);
}

// ---------------- LayerNorm: fp32 [rows][1024] -> bf16 ----------------
// ADDB: additionally write xwb[row] = x[row] + badd (prefill for atomic GEMMs)
template<bool ADDB>
__global__ __launch_bounds__(256) void ln_kernel(
    const float* __restrict__ x, const float* __restrict__ g,
    const float* __restrict__ b, u16* __restrict__ out,
    const float* __restrict__ badd, float* __restrict__ xwb)
{
  const int row = blockIdx.x;
  const int t = threadIdx.x;
  const float4 v = *reinterpret_cast<const float4*>(&x[(size_t)row*1024 + t*4]);
  float s  = v.x + v.y + v.z + v.w;
  float sq = v.x*v.x + v.y*v.y + v.z*v.z + v.w*v.w;
  #pragma unroll
  for (int off = 32; off; off >>= 1) { s += __shfl_down(s, off); sq += __shfl_down(sq, off); }
  __shared__ float red[8];
  const int wave = t >> 6, lane = t & 63;
  if (lane == 0) { red[wave] = s; red[wave + 4] = sq; }
  __syncthreads();
  __shared__ float stats[2];
  if (t == 0) {
    float S  = red[0] + red[1] + red[2] + red[3];
    float SQ = red[4] + red[5] + red[6] + red[7];
    float mu = S * (1.0f/1024.0f);
    float var = SQ * (1.0f/1024.0f) - mu*mu;
    stats[0] = mu; stats[1] = rsqrtf(var + 1e-5f);
  }
  __syncthreads();
  const float mu = stats[0], rv = stats[1];
  const float4 gv = *reinterpret_cast<const float4*>(&g[t*4]);
  const float4 bv = *reinterpret_cast<const float4*>(&b[t*4]);
  u16 o4[4];
  o4[0] = f2bf((v.x - mu)*rv*gv.x + bv.x);
  o4[1] = f2bf((v.y - mu)*rv*gv.y + bv.y);
  o4[2] = f2bf((v.z - mu)*rv*gv.z + bv.z);
  o4[3] = f2bf((v.w - mu)*rv*gv.w + bv.w);
  u32 p0 = (u32)o4[0] | ((u32)o4[1] << 16);
  u32 p1 = (u32)o4[2] | ((u32)o4[3] << 16);
  u32* op = reinterpret_cast<u32*>(&out[(size_t)row*1024 + t*4]);
  op[0] = p0; op[1] = p1;
  if (ADDB) {
    const float4 av = *reinterpret_cast<const float4*>(&badd[t*4]);
    float4 w;
    w.x = v.x + av.x; w.y = v.y + av.y; w.z = v.z + av.z; w.w = v.w + av.w;
    *reinterpret_cast<float4*>(&xwb[(size_t)row*1024 + t*4]) = w;
  }
}

// ------------- transpose + fp32->bf16 cast: in[R][C] -> out[C][R], batched -------------
__global__ __launch_bounds__(256) void transpose_cast(
    const float* __restrict__ in, u16* __restrict__ out, int R, int C)
{
  __shared__ float tile[32][33];
  const int tx = threadIdx.x, ty = threadIdx.y;
  const size_t bo = (size_t)blockIdx.z * R * C;
  const int r0 = blockIdx.y * 32, c0 = blockIdx.x * 32;
  #pragma unroll
  for (int j = 0; j < 4; ++j)
    tile[ty + j*8][tx] = in[bo + (size_t)(r0 + ty + j*8)*C + c0 + tx];
  __syncthreads();
  #pragma unroll
  for (int j = 0; j < 4; ++j)
    out[bo + (size_t)(c0 + ty + j*8)*R + r0 + tx] = f2bf(tile[tx][ty + j*8]);
}

// ------------- bf16 transpose: qkv V part [T][64] -> vt[bh][64][T] -------------
__global__ __launch_bounds__(256) void vt_kernel(
    const u16* __restrict__ qkv, u16* __restrict__ vt, int T)
{
  __shared__ u16 tile[32][33];
  const int tx = threadIdx.x, ty = threadIdx.y;
  const int bh = blockIdx.z, b = bh >> 4, h = bh & 15;
  const int r0 = blockIdx.x * 32;   // token tile
  const int c0 = blockIdx.y * 32;   // d tile
  const size_t tokbase = (size_t)b * T;
  #pragma unroll
  for (int j = 0; j < 4; ++j)
    tile[ty + j*8][tx] = qkv[(tokbase + r0 + ty + j*8)*3072 + 2048 + h*64 + c0 + tx];
  __syncthreads();
  #pragma unroll
  for (int j = 0; j < 4; ++j)
    vt[((size_t)bh*64 + c0 + ty + j*8)*T + r0 + tx] = tile[tx][ty + j*8];
}

// ------- GEMM 128x128, 8 waves, counted-vmcnt pipeline, swizzled LDS -------
// 2 barriers per K-step. out fp32 = acc + bias[n] + resid[m*N+n]
__global__ __launch_bounds__(512, 2) void gemm_128(
    const u16* __restrict__ A, const u16* __restrict__ BT,
    int M, int N, int K,
    const float* __restrict__ bias, const float* __restrict__ resid,
    float* __restrict__ Cout)
{
  __shared__ __align__(16) u16 Alds[2][128*64];
  __shared__ __align__(16) u16 Blds[2][128*64];
  const int t = threadIdx.x;
  const int wave = t >> 6, lane = t & 63;
  const int wm = wave >> 2, wn = wave & 3;     // 2 (M) x 4 (N)
  const int g = lane >> 4, r = lane & 15;
  const int m0 = blockIdx.y * 128, n0 = blockIdx.x * 128;
  const int NTk = K >> 6;

  f32x4 acc[4][2] = {};

  auto STAGE = [&](int buf, int kt) {
    const int k0 = kt << 6;
    #pragma unroll
    for (int p = 0; p < 2; ++p) {
      const int c = t + p*512;
      const int row = c >> 3;
      const int col = (((c & 7) ^ (row & 7)) << 3);
      gld16(&A[(size_t)(m0 + row)*K + k0 + col], &Alds[buf][c*8]);
    }
    #pragma unroll
    for (int p = 0; p < 2; ++p) {
      const int c = t + p*512;
      const int row = c >> 3;
      const int col = (((c & 7) ^ (row & 7)) << 3);
      gld16(&BT[(size_t)(n0 + row)*K + k0 + col], &Blds[buf][c*8]);
    }
  };

  STAGE(0, 0);
  if (NTk > 1) STAGE(1, 1);

  const int csw = (r & 7) << 3;   // u16-unit read-side swizzle

  for (int kt = 0; kt < NTk; ++kt) {
    const int buf = kt & 1;
    if (kt + 1 < NTk) asm volatile("s_waitcnt vmcnt(4)" ::: "memory");
    else              asm volatile("s_waitcnt vmcnt(0)" ::: "memory");
    __builtin_amdgcn_s_barrier();      // tile kt visible to all waves
    #pragma unroll
    for (int ks = 0; ks < 2; ++ks) {
      bf16x8 af[4], bfr[2];
      #pragma unroll
      for (int i = 0; i < 4; ++i)
        af[i] = *reinterpret_cast<const bf16x8*>(
            &Alds[buf][(wm*64 + i*16 + r)*64 + ((ks*32 + g*8) ^ csw)]);
      #pragma unroll
      for (int j = 0; j < 2; ++j)
        bfr[j] = *reinterpret_cast<const bf16x8*>(
            &Blds[buf][(wn*32 + j*16 + r)*64 + ((ks*32 + g*8) ^ csw)]);
      __builtin_amdgcn_s_setprio(1);
      #pragma unroll
      for (int i = 0; i < 4; ++i)
        #pragma unroll
        for (int j = 0; j < 2; ++j)
          acc[i][j] = __builtin_amdgcn_mfma_f32_16x16x32_bf16(af[i], bfr[j], acc[i][j], 0, 0, 0);
      __builtin_amdgcn_s_setprio(0);
    }
    __builtin_amdgcn_s_barrier();      // all reads of buf done -> safe to overwrite
    if (kt + 2 < NTk) STAGE(buf, kt + 2);
  }

  #pragma unroll
  for (int mi = 0; mi < 4; ++mi) {
    #pragma unroll
    for (int ni = 0; ni < 2; ++ni) {
      #pragma unroll
      for (int i = 0; i < 4; ++i) {
        const int gm = m0 + wm*64 + mi*16 + g*4 + i;
        const int gn = n0 + wn*32 + ni*16 + r;
        const size_t idx = (size_t)gm * N + gn;
        Cout[idx] = acc[mi][ni][i] + bias[gn] + resid[idx];
      }
    }
  }
}

// ------- GEMM 128x128 split-K=2, 4 waves x (64x64), atomic epilogue -------
// Higher fragment reuse: per K-tile/wave 16 ds_read_b128 feed 32 MFMAs
// (32 FLOP/LDS-byte, bt8-class). 64KB dbuf LDS -> 2 blocks/CU. Grid: flat
// 512 blocks = (8 n) x (32 m) x (2 k-half), XCD-grouped by m&7.
__global__ __launch_bounds__(256, 2) void gemm_128_sk(
    const u16* __restrict__ A, const u16* __restrict__ BT,
    int M, int N, int K, float* __restrict__ Cout)
{
  __shared__ __align__(16) u16 Alds[2][128*64];
  __shared__ __align__(16) u16 Blds[2][128*64];
  const int bid = blockIdx.x;
  const int s = bid >> 3;
  const int n0 = (s & 7) * 128;
  const int m0 = (((s >> 3) & 3) * 8 + (bid & 7)) * 128;
  const int kbase = (s >> 5) * (K >> 1);
  const int t = threadIdx.x;
  const int wave = t >> 6, lane = t & 63;
  const int wm = wave >> 1, wn = wave & 1;     // 2 (M) x 2 (N), 64x64 per wave
  const int g = lane >> 4, r = lane & 15;
  const int NTk = K >> 7;                      // (K/2)/64

  f32x4 acc[4][4] = {};

  auto STAGE = [&](int buf, int kt) {
    const int k0 = kbase + (kt << 6);
    #pragma unroll
    for (int p = 0; p < 4; ++p) {
      const int c = t + p*256;
      const int row = c >> 3;
      const int col = (((c & 7) ^ (row & 7)) << 3);
      gld16(&A[(size_t)(m0 + row)*K + k0 + col], &Alds[buf][c*8]);
    }
    #pragma unroll
    for (int p = 0; p < 4; ++p) {
      const int c = t + p*256;
      const int row = c >> 3;
      const int col = (((c & 7) ^ (row & 7)) << 3);
      gld16(&BT[(size_t)(n0 + row)*K + k0 + col], &Blds[buf][c*8]);
    }
  };

  STAGE(0, 0);
  if (NTk > 1) STAGE(1, 1);

  const int csw = (r & 7) << 3;

  for (int kt = 0; kt < NTk; ++kt) {
    const int buf = kt & 1;
    if (kt + 1 < NTk) asm volatile("s_waitcnt vmcnt(8)" ::: "memory");
    else              asm volatile("s_waitcnt vmcnt(0)" ::: "memory");
    __builtin_amdgcn_s_barrier();
    #pragma unroll
    for (int ks = 0; ks < 2; ++ks) {
      bf16x8 af[4], bfr[4];
      #pragma unroll
      for (int i = 0; i < 4; ++i) {
        af[i] = *reinterpret_cast<const bf16x8*>(
            &Alds[buf][(wm*64 + i*16 + r)*64 + ((ks*32 + g*8) ^ csw)]);
        bfr[i] = *reinterpret_cast<const bf16x8*>(
            &Blds[buf][(wn*64 + i*16 + r)*64 + ((ks*32 + g*8) ^ csw)]);
      }
      __builtin_amdgcn_s_setprio(1);
      #pragma unroll
      for (int i = 0; i < 4; ++i)
        #pragma unroll
        for (int j = 0; j < 4; ++j)
          acc[i][j] = __builtin_amdgcn_mfma_f32_16x16x32_bf16(af[i], bfr[j], acc[i][j], 0, 0, 0);
      __builtin_amdgcn_s_setprio(0);
    }
    __builtin_amdgcn_s_barrier();      // all reads of buf done -> safe to overwrite
    if (kt + 2 < NTk) STAGE(buf, kt + 2);
  }

  #pragma unroll
  for (int mi = 0; mi < 4; ++mi) {
    #pragma unroll
    for (int ni = 0; ni < 4; ++ni) {
      #pragma unroll
      for (int i = 0; i < 4; ++i) {
        const int gm = m0 + wm*64 + mi*16 + g*4 + i;
        const int gn = n0 + wn*64 + ni*16 + r;
        unsafeAtomicAdd(&Cout[(size_t)gm * N + gn], acc[mi][ni][i]);
      }
    }
  }
}

// ---------------- GEMM 256x256, BK=64, 8 waves, 4-phase counted-vmcnt ----------------
// EPI 0: out bf16, scale cols<1024 by 0.125*log2e (QKV fold)
// EPI 2: out bf16 = relu(acc + bias[n])
template<int EPI>
__global__ __launch_bounds__(512, 2) void gemm_bt8(
    const u16* __restrict__ A, const u16* __restrict__ BT,
    int M, int N, int K,
    const float* __restrict__ bias, void* __restrict__ Cout)
{
  __shared__ __align__(16) u16 Alds[2][256*64];
  __shared__ __align__(16) u16 Blds[2][256*64];
  const int t = threadIdx.x;
  const int wave = t >> 6, lane = t & 63;
  const int wm = wave >> 2, wn = wave & 3;     // 2 (M) x 4 (N)
  const int g = lane >> 4, r = lane & 15;
  const int m0 = blockIdx.y * 256, n0 = blockIdx.x * 256;
  const int NTk = K >> 6;

  f32x4 acc[8][4] = {};

  auto STAGE = [&](int buf, int kt) {
    const int k0 = kt << 6;
    #pragma unroll
    for (int p = 0; p < 4; ++p) {
      const int c = t + p*512;
      const int row = c >> 3;
      const int col = (((c & 7) ^ (row & 7)) << 3);
      gld16(&A[(size_t)(m0 + row)*K + k0 + col], &Alds[buf][c*8]);
    }
    #pragma unroll
    for (int p = 0; p < 4; ++p) {
      const int c = t + p*512;
      const int row = c >> 3;
      const int col = (((c & 7) ^ (row & 7)) << 3);
      gld16(&BT[(size_t)(n0 + row)*K + k0 + col], &Blds[buf][c*8]);
    }
  };

  STAGE(0, 0);
  if (NTk > 1) STAGE(1, 1);

  const int csw = (r & 7) << 3;   // u16-unit read-side swizzle

  for (int kt = 0; kt < NTk; ++kt) {
    const int buf = kt & 1;
    if (kt + 1 < NTk) asm volatile("s_waitcnt vmcnt(8)" ::: "memory");
    else              asm volatile("s_waitcnt vmcnt(0)" ::: "memory");
    __builtin_amdgcn_s_barrier();      // tile kt visible to all waves
    #pragma unroll
    for (int p = 0; p < 4; ++p) {
      const int ks = p >> 1, mih = p & 1;
      bf16x8 af[4], bfr[4];
      #pragma unroll
      for (int i = 0; i < 4; ++i) {
        af[i] = *reinterpret_cast<const bf16x8*>(
            &Alds[buf][(wm*128 + (mih*4 + i)*16 + r)*64 + ((ks*32 + g*8) ^ csw)]);
        bfr[i] = *reinterpret_cast<const bf16x8*>(
            &Blds[buf][(wn*64 + i*16 + r)*64 + ((ks*32 + g*8) ^ csw)]);
      }
      __builtin_amdgcn_s_setprio(1);
      #pragma unroll
      for (int i = 0; i < 4; ++i)
        #pragma unroll
        for (int j = 0; j < 4; ++j)
          acc[mih*4 + i][j] =
              __builtin_amdgcn_mfma_f32_16x16x32_bf16(af[i], bfr[j], acc[mih*4 + i][j], 0, 0, 0);
      __builtin_amdgcn_s_setprio(0);
      __builtin_amdgcn_s_barrier();    // phase lockstep; final one = overwrite guard
    }
    if (kt + 2 < NTk) STAGE(buf, kt + 2);
  }

  #pragma unroll
  for (int mi = 0; mi < 8; ++mi) {
    #pragma unroll
    for (int ni = 0; ni < 4; ++ni) {
      #pragma unroll
      for (int i = 0; i < 4; ++i) {
        const int gm = m0 + wm*128 + mi*16 + g*4 + i;
        const int gn = n0 + wn*64 + ni*16 + r;
        const size_t idx = (size_t)gm * N + gn;
        float v = acc[mi][ni][i];
        if (EPI == 0) {
          const float sc = (gn < 1024) ? 0.18033688011112042f : 1.0f;
          ((u16*)Cout)[idx] = f2bf(v * sc);
        } else {
          v += bias[gn];
          ((u16*)Cout)[idx] = f2bf(v > 0.f ? v : 0.f);
        }
      }
    }
  }
}

// ---------------- causal flash attention ----------------
// qkv: [B*T][3072] bf16 (q|k|v), q pre-scaled by 0.125*log2e; vt: [32][64][T] bf16
// Uniform-work blocks: q-tile pair (31-qb, qb) sequentially; grid 512.
// Counted-vmcnt pipeline: raw barriers, vmcnt(4) mid-loop so next tile's
// global_load_lds stays in flight across the barrier (no full drain per tile).
__global__ __launch_bounds__(256, 4) void attn_kernel(
    const u16* __restrict__ qkv, const u16* __restrict__ vt,
    u16* __restrict__ o, int T)
{
  const int bid = blockIdx.x;                 // 0..511
  const int bh  = ((bid & 7) << 2) | ((bid >> 3) & 3);  // 4 heads per XCD
  const int qb  = bid >> 5;                   // 0..15
  const int b = bh >> 4, h = bh & 15;
  const int t = threadIdx.x;
  const int wave = t >> 6, lane = t & 63;
  const int g = lane >> 4, r = lane & 15;
  const size_t tokbase = (size_t)b * T;

  __shared__ __align__(16) u16 Klds[2][64*64];
  __shared__ __align__(16) u16 Vlds[2][64*64];
  __shared__ __align__(16) u16 P[4][16*64];

  bf16x8 ones;
  #pragma unroll
  for (int i = 0; i < 8; ++i) ones[i] = (bf16)1.0f;

  auto STAGE = [&](int buf, int kb) {
    const int kv0 = kb*64;
    #pragma unroll
    for (int p = 0; p < 2; ++p) {
      const int c2 = t + p*256;
      const int row = c2 >> 3;
      const int scol = ((c2 & 7) ^ (row & 7)) << 3;   // pre-swizzled source col
      gld16(&qkv[(tokbase + kv0 + row)*3072 + 1024 + h*64 + scol], &Klds[buf][c2*8]);
      gld16(&vt[((size_t)bh*64 + row)*T + kv0 + scol], &Vlds[buf][c2*8]);
    }
  };

  #pragma unroll 1
  for (int ph = 0; ph < 2; ++ph) {
    const int qa = ph ? qb : (31 - qb);       // long tile first
    const int q0 = qa*64 + wave*16;
    if (ph) __syncthreads();                  // full drain between phases

    bf16x8 qf[2];
    #pragma unroll
    for (int ks = 0; ks < 2; ++ks)
      qf[ks] = *reinterpret_cast<const bf16x8*>(
          &qkv[(tokbase + q0 + r)*3072 + h*64 + ks*32 + g*8]);

    f32x4 acc_o[4] = {};
    f32x4 acc_l = {};
    const int nkv = qa + 1;

    STAGE(0, 0);
    int cur = 0;
    for (int kb = 0; kb < nkv; ++kb) {
      __builtin_amdgcn_s_barrier();          // WAR gate: all waves done reading buf cur^1
      if (kb + 1 < nkv) {
        STAGE(cur ^ 1, kb + 1);              // issue next tile's 4 loads
        asm volatile("s_waitcnt vmcnt(4)" ::: "memory");  // cur tile landed; next in flight
      } else {
        asm volatile("s_waitcnt vmcnt(0)" ::: "memory");
      }
      __builtin_amdgcn_s_barrier();          // all waves' cur-tile loads landed
      const int kv0 = kb*64;
      const bool diag = (kb == qa);
      const int cb = (r & 7) << 3;           // read-side swizzle (u16 units)

      // S = Q K^T : 16q x 64kv per wave (log2-domain logits)
      f32x4 s[4] = {};
      #pragma unroll
      for (int nb = 0; nb < 4; ++nb) {
        #pragma unroll
        for (int ks = 0; ks < 2; ++ks) {
          bf16x8 kf = *reinterpret_cast<const bf16x8*>(
              &Klds[cur][(nb*16 + r)*64 + ((ks*32 + g*8) ^ cb)]);
          s[nb] = __builtin_amdgcn_mfma_f32_16x16x32_bf16(qf[ks], kf, s[nb], 0, 0, 0);
        }
      }
      // P = exp2(S); causal zero-mask on diagonal tile only
      #pragma unroll
      for (int i = 0; i < 4; ++i) {
        const int prow = g*4 + i;
        const int pcb = (prow & 7) << 3;
        #pragma unroll
        for (int nb = 0; nb < 4; ++nb) {
          float pv = __builtin_amdgcn_exp2f(s[nb][i]);
          if (diag && (kv0 + nb*16 + r > q0 + prow)) pv = 0.f;
          const bf16 bv = (bf16)pv;          // native RNE cvt
          P[wave][prow*64 + ((nb*16 + r) ^ pcb)] = __builtin_bit_cast(u16, bv);
        }
      }
      // O += P * V ; row-sum l += P * ones
      #pragma unroll
      for (int ks = 0; ks < 2; ++ks) {
        bf16x8 pf = *reinterpret_cast<const bf16x8*>(
            &P[wave][r*64 + ((ks*32 + g*8) ^ cb)]);
        acc_l = __builtin_amdgcn_mfma_f32_16x16x32_bf16(pf, ones, acc_l, 0, 0, 0);
        #pragma unroll
        for (int nt = 0; nt < 4; ++nt) {
          bf16x8 vf = *reinterpret_cast<const bf16x8*>(
              &Vlds[cur][(nt*16 + r)*64 + ((ks*32 + g*8) ^ cb)]);
          acc_o[nt] = __builtin_amdgcn_mfma_f32_16x16x32_bf16(pf, vf, acc_o[nt], 0, 0, 0);
        }
      }
      cur ^= 1;
    }
    #pragma unroll
    for (int i = 0; i < 4; ++i) {
      const float inv = 1.0f / acc_l[i];
      const size_t rowo = (tokbase + q0 + g*4 + i) * 1024;
      #pragma unroll
      for (int nt = 0; nt < 4; ++nt) {
        const bf16 bv = (bf16)(acc_o[nt][i] * inv);
        o[rowo + h*64 + nt*16 + r] = __builtin_bit_cast(u16, bv);
      }
    }
  }
}

extern "C" void kernel_launch(void* const* d_in, const int* in_sizes, int n_in,
                              void* d_out, int out_size, void* d_ws, size_t ws_size,
                              hipStream_t stream)
{
  const float* x      = (const float*)d_in[0];
  const float* wq     = (const float*)d_in[1];
  const float* wk     = (const float*)d_in[2];
  const float* wv     = (const float*)d_in[3];
  const float* w_proj = (const float*)d_in[4];
  const float* b_proj = (const float*)d_in[5];
  const float* w_ff1  = (const float*)d_in[6];
  const float* b_ff1  = (const float*)d_in[7];
  const float* w_ff2  = (const float*)d_in[8];
  const float* b_ff2  = (const float*)d_in[9];
  const float* ln1_g  = (const float*)d_in[10];
  const float* ln1_b  = (const float*)d_in[11];
  const float* ln2_g  = (const float*)d_in[12];
  const float* ln2_b  = (const float*)d_in[13];

  const int T = 2048;
  const int NT = 4096;   // B*T

  char* ws = (char*)d_ws;
  u16* Wbuf   = (u16*)(ws);                       // weight^T buffer, up to 8 MB
  u16* hbuf   = (u16*)(ws + ((size_t)8  << 20));  // LN output, 8 MB
  u16* qkvbuf = (u16*)(ws + ((size_t)16 << 20));  // 24 MB
  u16* obuf   = (u16*)(ws + ((size_t)40 << 20));  // 8 MB
  u16* ff1buf = qkvbuf;                           // 32 MB spans qkv+o region
  u16* vtbuf  = Wbuf;                             // aliased: lifetime disjoint from Wbuf uses
  float* x1   = (float*)d_out;                    // post-attn residual lives in d_out

  // LN1
  ln_kernel<false><<<dim3(NT), dim3(256), 0, stream>>>(x, ln1_g, ln1_b, hbuf, nullptr, nullptr);
  // W_qkv^T (per-head transpose [1024][64] -> [64][1024], 16 heads each)
  transpose_cast<<<dim3(2, 32, 16), dim3(32, 8), 0, stream>>>(wq, Wbuf + 0*1024*1024, 1024, 64);
  transpose_cast<<<dim3(2, 32, 16), dim3(32, 8), 0, stream>>>(wk, Wbuf + 1*1024*1024, 1024, 64);
  transpose_cast<<<dim3(2, 32, 16), dim3(32, 8), 0, stream>>>(wv, Wbuf + 2*1024*1024, 1024, 64);
  // QKV projection (q pre-scaled by 0.125*log2e in epilogue) - 256^2 pipeline
  gemm_bt8<0><<<dim3(12, 16), dim3(512), 0, stream>>>(hbuf, Wbuf, NT, 3072, 1024, nullptr, qkvbuf);
  // V^T for attention (after QKV gemm has finished reading Wbuf)
  vt_kernel<<<dim3(64, 2, 32), dim3(32, 8), 0, stream>>>(qkvbuf, vtbuf, T);
  // attention (uniform-work paired q-tiles, counted-vmcnt pipeline)
  attn_kernel<<<dim3(512), dim3(256), 0, stream>>>(qkvbuf, vtbuf, obuf, T);
  // output projection + bias + residual -> x1 (in d_out)
  transpose_cast<<<dim3(32, 32, 1), dim3(32, 8), 0, stream>>>(w_proj, Wbuf, 1024, 1024);
  gemm_128<<<dim3(8, 32), dim3(512), 0, stream>>>(obuf, Wbuf, NT, 1024, 1024, b_proj, x, x1);
  // LN2 (+ prefill x1 += b_ff2 for FF2's atomic split-K)
  ln_kernel<true><<<dim3(NT), dim3(256), 0, stream>>>(x1, ln2_g, ln2_b, hbuf, b_ff2, x1);
  // FF1 + bias + relu - 256^2 pipeline
  transpose_cast<<<dim3(128, 32, 1), dim3(32, 8), 0, stream>>>(w_ff1, Wbuf, 1024, 4096);
  gemm_bt8<2><<<dim3(16, 16), dim3(512), 0, stream>>>(hbuf, Wbuf, NT, 4096, 1024, b_ff1, ff1buf);
  // FF2: 128^2 split-K=2, 4-wave 64x64, atomic into prefilled x1 (d_out)
  transpose_cast<<<dim3(32, 128, 1), dim3(32, 8), 0, stream>>>(w_ff2, Wbuf, 4096, 1024);
  gemm_128_sk<<<dim3(512), dim3(256), 0, stream>>>(ff1buf, Wbuf, NT, 1024, 4096, (float*)d_out);
}

// Round 16
// 238.372 us; speedup vs baseline: 1.0198x; 1.0198x over previous
//
#include <hip/hip_runtime.h>

typedef unsigned short u16;
typedef unsigned int   u32;
typedef __bf16 bf16;
typedef bf16 bf16x8 __attribute__((ext_vector_type(8)));
typedef float f32x4 __attribute__((ext_vector_type(4)));
typedef u32 u32x4 __attribute__((ext_vector_type(4)));

__device__ inline u16 f2bf(float f) {
  union { float f; u32 u; } cv; cv.f = f;
  u32 u = cv.u;
  return (u16)((u + 0x7FFFu + ((u >> 16) & 1u)) >> 16);
}

__device__ __forceinline__ void gld16(const void* g, void* l) {
  __builtin_amdgcn_global_load_lds(
      (const __attribute__((address_space(1))) void*)g,
      (__attribute__((address_space(3))) void*)l, 16, 0, 0);
}

// ---------------- LayerNorm: fp32 [rows][1024] -> bf16 ----------------
// ADDB: additionally write xwb[row] = x[row] + badd (prefill for atomic GEMMs)
template<bool ADDB>
__global__ __launch_bounds__(256) void ln_kernel(
    const float* __restrict__ x, const float* __restrict__ g,
    const float* __restrict__ b, u16* __restrict__ out,
    const float* __restrict__ badd, float* __restrict__ xwb)
{
  const int row = blockIdx.x;
  const int t = threadIdx.x;
  const float4 v = *reinterpret_cast<const float4*>(&x[(size_t)row*1024 + t*4]);
  float s  = v.x + v.y + v.z + v.w;
  float sq = v.x*v.x + v.y*v.y + v.z*v.z + v.w*v.w;
  #pragma unroll
  for (int off = 32; off; off >>= 1) { s += __shfl_down(s, off); sq += __shfl_down(sq, off); }
  __shared__ float red[8];
  const int wave = t >> 6, lane = t & 63;
  if (lane == 0) { red[wave] = s; red[wave + 4] = sq; }
  __syncthreads();
  __shared__ float stats[2];
  if (t == 0) {
    float S  = red[0] + red[1] + red[2] + red[3];
    float SQ = red[4] + red[5] + red[6] + red[7];
    float mu = S * (1.0f/1024.0f);
    float var = SQ * (1.0f/1024.0f) - mu*mu;
    stats[0] = mu; stats[1] = rsqrtf(var + 1e-5f);
  }
  __syncthreads();
  const float mu = stats[0], rv = stats[1];
  const float4 gv = *reinterpret_cast<const float4*>(&g[t*4]);
  const float4 bv = *reinterpret_cast<const float4*>(&b[t*4]);
  u16 o4[4];
  o4[0] = f2bf((v.x - mu)*rv*gv.x + bv.x);
  o4[1] = f2bf((v.y - mu)*rv*gv.y + bv.y);
  o4[2] = f2bf((v.z - mu)*rv*gv.z + bv.z);
  o4[3] = f2bf((v.w - mu)*rv*gv.w + bv.w);
  u32 p0 = (u32)o4[0] | ((u32)o4[1] << 16);
  u32 p1 = (u32)o4[2] | ((u32)o4[3] << 16);
  u32* op = reinterpret_cast<u32*>(&out[(size_t)row*1024 + t*4]);
  op[0] = p0; op[1] = p1;
  if (ADDB) {
    const float4 av = *reinterpret_cast<const float4*>(&badd[t*4]);
    float4 w;
    w.x = v.x + av.x; w.y = v.y + av.y; w.z = v.z + av.z; w.w = v.w + av.w;
    *reinterpret_cast<float4*>(&xwb[(size_t)row*1024 + t*4]) = w;
  }
}

// ------------- transpose + fp32->bf16 cast: in[R][C] -> out[C][R], batched -------------
__global__ __launch_bounds__(256) void transpose_cast(
    const float* __restrict__ in, u16* __restrict__ out, int R, int C)
{
  __shared__ float tile[32][33];
  const int tx = threadIdx.x, ty = threadIdx.y;
  const size_t bo = (size_t)blockIdx.z * R * C;
  const int r0 = blockIdx.y * 32, c0 = blockIdx.x * 32;
  #pragma unroll
  for (int j = 0; j < 4; ++j)
    tile[ty + j*8][tx] = in[bo + (size_t)(r0 + ty + j*8)*C + c0 + tx];
  __syncthreads();
  #pragma unroll
  for (int j = 0; j < 4; ++j)
    out[bo + (size_t)(c0 + ty + j*8)*R + r0 + tx] = f2bf(tile[tx][ty + j*8]);
}

// ------------- bf16 transpose: qkv V part [T][64] -> vt[bh][64][T] -------------
__global__ __launch_bounds__(256) void vt_kernel(
    const u16* __restrict__ qkv, u16* __restrict__ vt, int T)
{
  __shared__ u16 tile[32][33];
  const int tx = threadIdx.x, ty = threadIdx.y;
  const int bh = blockIdx.z, b = bh >> 4, h = bh & 15;
  const int r0 = blockIdx.x * 32;   // token tile
  const int c0 = blockIdx.y * 32;   // d tile
  const size_t tokbase = (size_t)b * T;
  #pragma unroll
  for (int j = 0; j < 4; ++j)
    tile[ty + j*8][tx] = qkv[(tokbase + r0 + ty + j*8)*3072 + 2048 + h*64 + c0 + tx];
  __syncthreads();
  #pragma unroll
  for (int j = 0; j < 4; ++j)
    vt[((size_t)bh*64 + c0 + ty + j*8)*T + r0 + tx] = tile[tx][ty + j*8];
}

// ------- GEMM 128x128, 8 waves, counted-vmcnt pipeline, swizzled LDS -------
// 2 barriers per K-step. out fp32 = acc + bias[n] + resid[m*N+n]
__global__ __launch_bounds__(512, 2) void gemm_128(
    const u16* __restrict__ A, const u16* __restrict__ BT,
    int M, int N, int K,
    const float* __restrict__ bias, const float* __restrict__ resid,
    float* __restrict__ Cout)
{
  __shared__ __align__(16) u16 Alds[2][128*64];
  __shared__ __align__(16) u16 Blds[2][128*64];
  const int t = threadIdx.x;
  const int wave = t >> 6, lane = t & 63;
  const int wm = wave >> 2, wn = wave & 3;     // 2 (M) x 4 (N)
  const int g = lane >> 4, r = lane & 15;
  const int m0 = blockIdx.y * 128, n0 = blockIdx.x * 128;
  const int NTk = K >> 6;

  f32x4 acc[4][2] = {};

  auto STAGE = [&](int buf, int kt) {
    const int k0 = kt << 6;
    #pragma unroll
    for (int p = 0; p < 2; ++p) {
      const int c = t + p*512;
      const int row = c >> 3;
      const int col = (((c & 7) ^ (row & 7)) << 3);
      gld16(&A[(size_t)(m0 + row)*K + k0 + col], &Alds[buf][c*8]);
    }
    #pragma unroll
    for (int p = 0; p < 2; ++p) {
      const int c = t + p*512;
      const int row = c >> 3;
      const int col = (((c & 7) ^ (row & 7)) << 3);
      gld16(&BT[(size_t)(n0 + row)*K + k0 + col], &Blds[buf][c*8]);
    }
  };

  STAGE(0, 0);
  if (NTk > 1) STAGE(1, 1);

  const int csw = (r & 7) << 3;   // u16-unit read-side swizzle

  for (int kt = 0; kt < NTk; ++kt) {
    const int buf = kt & 1;
    if (kt + 1 < NTk) asm volatile("s_waitcnt vmcnt(4)" ::: "memory");
    else              asm volatile("s_waitcnt vmcnt(0)" ::: "memory");
    __builtin_amdgcn_s_barrier();      // tile kt visible to all waves
    #pragma unroll
    for (int ks = 0; ks < 2; ++ks) {
      bf16x8 af[4], bfr[2];
      #pragma unroll
      for (int i = 0; i < 4; ++i)
        af[i] = *reinterpret_cast<const bf16x8*>(
            &Alds[buf][(wm*64 + i*16 + r)*64 + ((ks*32 + g*8) ^ csw)]);
      #pragma unroll
      for (int j = 0; j < 2; ++j)
        bfr[j] = *reinterpret_cast<const bf16x8*>(
            &Blds[buf][(wn*32 + j*16 + r)*64 + ((ks*32 + g*8) ^ csw)]);
      __builtin_amdgcn_s_setprio(1);
      #pragma unroll
      for (int i = 0; i < 4; ++i)
        #pragma unroll
        for (int j = 0; j < 2; ++j)
          acc[i][j] = __builtin_amdgcn_mfma_f32_16x16x32_bf16(af[i], bfr[j], acc[i][j], 0, 0, 0);
      __builtin_amdgcn_s_setprio(0);
    }
    __builtin_amdgcn_s_barrier();      // all reads of buf done -> safe to overwrite
    if (kt + 2 < NTk) STAGE(buf, kt + 2);
  }

  #pragma unroll
  for (int mi = 0; mi < 4; ++mi) {
    #pragma unroll
    for (int ni = 0; ni < 2; ++ni) {
      #pragma unroll
      for (int i = 0; i < 4; ++i) {
        const int gm = m0 + wm*64 + mi*16 + g*4 + i;
        const int gn = n0 + wn*32 + ni*16 + r;
        const size_t idx = (size_t)gm * N + gn;
        Cout[idx] = acc[mi][ni][i] + bias[gn] + resid[idx];
      }
    }
  }
}

// ------- GEMM 128x128 split-K=2, 8 waves, atomic-add epilogue -------
// 2 barriers per K-step. Grid: flat 512 blocks = (8 n) x (32 m) x (2 k-half),
// XCD-grouped by m&7 so same-m blocks (sharing the A panel) share an XCD L2.
__global__ __launch_bounds__(512, 2) void gemm_128_sk(
    const u16* __restrict__ A, const u16* __restrict__ BT,
    int M, int N, int K, float* __restrict__ Cout)
{
  __shared__ __align__(16) u16 Alds[2][128*64];
  __shared__ __align__(16) u16 Blds[2][128*64];
  const int bid = blockIdx.x;
  const int s = bid >> 3;
  const int n0 = (s & 7) * 128;
  const int m0 = (((s >> 3) & 3) * 8 + (bid & 7)) * 128;
  const int kbase = (s >> 5) * (K >> 1);
  const int t = threadIdx.x;
  const int wave = t >> 6, lane = t & 63;
  const int wm = wave >> 2, wn = wave & 3;
  const int g = lane >> 4, r = lane & 15;
  const int NTk = K >> 7;                      // (K/2)/64

  f32x4 acc[4][2] = {};

  auto STAGE = [&](int buf, int kt) {
    const int k0 = kbase + (kt << 6);
    #pragma unroll
    for (int p = 0; p < 2; ++p) {
      const int c = t + p*512;
      const int row = c >> 3;
      const int col = (((c & 7) ^ (row & 7)) << 3);
      gld16(&A[(size_t)(m0 + row)*K + k0 + col], &Alds[buf][c*8]);
    }
    #pragma unroll
    for (int p = 0; p < 2; ++p) {
      const int c = t + p*512;
      const int row = c >> 3;
      const int col = (((c & 7) ^ (row & 7)) << 3);
      gld16(&BT[(size_t)(n0 + row)*K + k0 + col], &Blds[buf][c*8]);
    }
  };

  STAGE(0, 0);
  if (NTk > 1) STAGE(1, 1);

  const int csw = (r & 7) << 3;

  for (int kt = 0; kt < NTk; ++kt) {
    const int buf = kt & 1;
    if (kt + 1 < NTk) asm volatile("s_waitcnt vmcnt(4)" ::: "memory");
    else              asm volatile("s_waitcnt vmcnt(0)" ::: "memory");
    __builtin_amdgcn_s_barrier();
    #pragma unroll
    for (int ks = 0; ks < 2; ++ks) {
      bf16x8 af[4], bfr[2];
      #pragma unroll
      for (int i = 0; i < 4; ++i)
        af[i] = *reinterpret_cast<const bf16x8*>(
            &Alds[buf][(wm*64 + i*16 + r)*64 + ((ks*32 + g*8) ^ csw)]);
      #pragma unroll
      for (int j = 0; j < 2; ++j)
        bfr[j] = *reinterpret_cast<const bf16x8*>(
            &Blds[buf][(wn*32 + j*16 + r)*64 + ((ks*32 + g*8) ^ csw)]);
      __builtin_amdgcn_s_setprio(1);
      #pragma unroll
      for (int i = 0; i < 4; ++i)
        #pragma unroll
        for (int j = 0; j < 2; ++j)
          acc[i][j] = __builtin_amdgcn_mfma_f32_16x16x32_bf16(af[i], bfr[j], acc[i][j], 0, 0, 0);
      __builtin_amdgcn_s_setprio(0);
    }
    __builtin_amdgcn_s_barrier();      // all reads of buf done -> safe to overwrite
    if (kt + 2 < NTk) STAGE(buf, kt + 2);
  }

  #pragma unroll
  for (int mi = 0; mi < 4; ++mi) {
    #pragma unroll
    for (int ni = 0; ni < 2; ++ni) {
      #pragma unroll
      for (int i = 0; i < 4; ++i) {
        const int gm = m0 + wm*64 + mi*16 + g*4 + i;
        const int gn = n0 + wn*32 + ni*16 + r;
        unsafeAtomicAdd(&Cout[(size_t)gm * N + gn], acc[mi][ni][i]);
      }
    }
  }
}

// ---------------- GEMM 256x256, BK=64, 8 waves, 4-phase counted-vmcnt ----------------
// EPI 2: out bf16 = relu(acc + bias[n])  (FF1)
template<int EPI>
__global__ __launch_bounds__(512, 2) void gemm_bt8(
    const u16* __restrict__ A, const u16* __restrict__ BT,
    int M, int N, int K,
    const float* __restrict__ bias, void* __restrict__ Cout)
{
  __shared__ __align__(16) u16 Alds[2][256*64];
  __shared__ __align__(16) u16 Blds[2][256*64];
  const int t = threadIdx.x;
  const int wave = t >> 6, lane = t & 63;
  const int wm = wave >> 2, wn = wave & 3;     // 2 (M) x 4 (N)
  const int g = lane >> 4, r = lane & 15;
  const int m0 = blockIdx.y * 256, n0 = blockIdx.x * 256;
  const int NTk = K >> 6;

  f32x4 acc[8][4] = {};

  auto STAGE = [&](int buf, int kt) {
    const int k0 = kt << 6;
    #pragma unroll
    for (int p = 0; p < 4; ++p) {
      const int c = t + p*512;
      const int row = c >> 3;
      const int col = (((c & 7) ^ (row & 7)) << 3);
      gld16(&A[(size_t)(m0 + row)*K + k0 + col], &Alds[buf][c*8]);
    }
    #pragma unroll
    for (int p = 0; p < 4; ++p) {
      const int c = t + p*512;
      const int row = c >> 3;
      const int col = (((c & 7) ^ (row & 7)) << 3);
      gld16(&BT[(size_t)(n0 + row)*K + k0 + col], &Blds[buf][c*8]);
    }
  };

  STAGE(0, 0);
  if (NTk > 1) STAGE(1, 1);

  const int csw = (r & 7) << 3;   // u16-unit read-side swizzle

  for (int kt = 0; kt < NTk; ++kt) {
    const int buf = kt & 1;
    if (kt + 1 < NTk) asm volatile("s_waitcnt vmcnt(8)" ::: "memory");
    else              asm volatile("s_waitcnt vmcnt(0)" ::: "memory");
    __builtin_amdgcn_s_barrier();      // tile kt visible to all waves
    #pragma unroll
    for (int p = 0; p < 4; ++p) {
      const int ks = p >> 1, mih = p & 1;
      bf16x8 af[4], bfr[4];
      #pragma unroll
      for (int i = 0; i < 4; ++i) {
        af[i] = *reinterpret_cast<const bf16x8*>(
            &Alds[buf][(wm*128 + (mih*4 + i)*16 + r)*64 + ((ks*32 + g*8) ^ csw)]);
        bfr[i] = *reinterpret_cast<const bf16x8*>(
            &Blds[buf][(wn*64 + i*16 + r)*64 + ((ks*32 + g*8) ^ csw)]);
      }
      __builtin_amdgcn_s_setprio(1);
      #pragma unroll
      for (int i = 0; i < 4; ++i)
        #pragma unroll
        for (int j = 0; j < 4; ++j)
          acc[mih*4 + i][j] =
              __builtin_amdgcn_mfma_f32_16x16x32_bf16(af[i], bfr[j], acc[mih*4 + i][j], 0, 0, 0);
      __builtin_amdgcn_s_setprio(0);
      __builtin_amdgcn_s_barrier();    // phase lockstep; final one = overwrite guard
    }
    if (kt + 2 < NTk) STAGE(buf, kt + 2);
  }

  #pragma unroll
  for (int mi = 0; mi < 8; ++mi) {
    #pragma unroll
    for (int ni = 0; ni < 4; ++ni) {
      #pragma unroll
      for (int i = 0; i < 4; ++i) {
        const int gm = m0 + wm*128 + mi*16 + g*4 + i;
        const int gn = n0 + wn*64 + ni*16 + r;
        const size_t idx = (size_t)gm * N + gn;
        float v = acc[mi][ni][i] + bias[gn];
        ((u16*)Cout)[idx] = f2bf(v > 0.f ? v : 0.f);
      }
    }
  }
}

// ------- GEMM 256x192 (QKV): bt8 pipeline, full 256-block grid -------
// N=3072 = 16 x 192 -> grid (16,16) = 256 blocks (no idle CUs).
// 8 waves as 2M x 4N, per wave 128x48 (3 B-fragments). 112 KB LDS.
// out bf16, scale cols<1024 by 0.125*log2e (q-scale + exp2 fold).
__global__ __launch_bounds__(512, 2) void gemm_qkv(
    const u16* __restrict__ A, const u16* __restrict__ BT,
    int M, int N, int K, u16* __restrict__ Cout)
{
  __shared__ __align__(16) u16 Alds[2][256*64];
  __shared__ __align__(16) u16 Blds[2][192*64];
  const int t = threadIdx.x;
  const int wave = t >> 6, lane = t & 63;
  const int wm = wave >> 2, wn = wave & 3;     // 2 (M) x 4 (N)
  const int g = lane >> 4, r = lane & 15;
  const int m0 = blockIdx.y * 256, n0 = blockIdx.x * 192;
  const int NTk = K >> 6;

  f32x4 acc[8][3] = {};

  auto STAGE = [&](int buf, int kt) {
    const int k0 = kt << 6;
    #pragma unroll
    for (int p = 0; p < 4; ++p) {
      const int c = t + p*512;
      const int row = c >> 3;
      const int col = (((c & 7) ^ (row & 7)) << 3);
      gld16(&A[(size_t)(m0 + row)*K + k0 + col], &Alds[buf][c*8]);
    }
    #pragma unroll
    for (int p = 0; p < 3; ++p) {
      const int c = t + p*512;
      const int row = c >> 3;
      const int col = (((c & 7) ^ (row & 7)) << 3);
      gld16(&BT[(size_t)(n0 + row)*K + k0 + col], &Blds[buf][c*8]);
    }
  };

  STAGE(0, 0);
  if (NTk > 1) STAGE(1, 1);

  const int csw = (r & 7) << 3;   // u16-unit read-side swizzle

  for (int kt = 0; kt < NTk; ++kt) {
    const int buf = kt & 1;
    if (kt + 1 < NTk) asm volatile("s_waitcnt vmcnt(7)" ::: "memory");
    else              asm volatile("s_waitcnt vmcnt(0)" ::: "memory");
    __builtin_amdgcn_s_barrier();      // tile kt visible to all waves
    #pragma unroll
    for (int p = 0; p < 4; ++p) {
      const int ks = p >> 1, mih = p & 1;
      bf16x8 af[4], bfr[3];
      #pragma unroll
      for (int i = 0; i < 4; ++i)
        af[i] = *reinterpret_cast<const bf16x8*>(
            &Alds[buf][(wm*128 + (mih*4 + i)*16 + r)*64 + ((ks*32 + g*8) ^ csw)]);
      #pragma unroll
      for (int j = 0; j < 3; ++j)
        bfr[j] = *reinterpret_cast<const bf16x8*>(
            &Blds[buf][(wn*48 + j*16 + r)*64 + ((ks*32 + g*8) ^ csw)]);
      __builtin_amdgcn_s_setprio(1);
      #pragma unroll
      for (int i = 0; i < 4; ++i)
        #pragma unroll
        for (int j = 0; j < 3; ++j)
          acc[mih*4 + i][j] =
              __builtin_amdgcn_mfma_f32_16x16x32_bf16(af[i], bfr[j], acc[mih*4 + i][j], 0, 0, 0);
      __builtin_amdgcn_s_setprio(0);
      __builtin_amdgcn_s_barrier();    // phase lockstep; final one = overwrite guard
    }
    if (kt + 2 < NTk) STAGE(buf, kt + 2);
  }

  #pragma unroll
  for (int mi = 0; mi < 8; ++mi) {
    #pragma unroll
    for (int ni = 0; ni < 3; ++ni) {
      #pragma unroll
      for (int i = 0; i < 4; ++i) {
        const int gm = m0 + wm*128 + mi*16 + g*4 + i;
        const int gn = n0 + wn*48 + ni*16 + r;
        const float sc = (gn < 1024) ? 0.18033688011112042f : 1.0f;
        Cout[(size_t)gm * N + gn] = f2bf(acc[mi][ni][i] * sc);
      }
    }
  }
}

// ---------------- causal flash attention ----------------
// qkv: [B*T][3072] bf16 (q|k|v), q pre-scaled by 0.125*log2e; vt: [32][64][T] bf16
// Uniform-work blocks: q-tile pair (31-qb, qb) sequentially; grid 512.
// Counted-vmcnt pipeline: raw barriers, vmcnt(4) mid-loop so next tile's
// global_load_lds stays in flight across the barrier (no full drain per tile).
__global__ __launch_bounds__(256, 4) void attn_kernel(
    const u16* __restrict__ qkv, const u16* __restrict__ vt,
    u16* __restrict__ o, int T)
{
  const int bid = blockIdx.x;                 // 0..511
  const int bh  = ((bid & 7) << 2) | ((bid >> 3) & 3);  // 4 heads per XCD
  const int qb  = bid >> 5;                   // 0..15
  const int b = bh >> 4, h = bh & 15;
  const int t = threadIdx.x;
  const int wave = t >> 6, lane = t & 63;
  const int g = lane >> 4, r = lane & 15;
  const size_t tokbase = (size_t)b * T;

  __shared__ __align__(16) u16 Klds[2][64*64];
  __shared__ __align__(16) u16 Vlds[2][64*64];
  __shared__ __align__(16) u16 P[4][16*64];

  bf16x8 ones;
  #pragma unroll
  for (int i = 0; i < 8; ++i) ones[i] = (bf16)1.0f;

  auto STAGE = [&](int buf, int kb) {
    const int kv0 = kb*64;
    #pragma unroll
    for (int p = 0; p < 2; ++p) {
      const int c2 = t + p*256;
      const int row = c2 >> 3;
      const int scol = ((c2 & 7) ^ (row & 7)) << 3;   // pre-swizzled source col
      gld16(&qkv[(tokbase + kv0 + row)*3072 + 1024 + h*64 + scol], &Klds[buf][c2*8]);
      gld16(&vt[((size_t)bh*64 + row)*T + kv0 + scol], &Vlds[buf][c2*8]);
    }
  };

  #pragma unroll 1
  for (int ph = 0; ph < 2; ++ph) {
    const int qa = ph ? qb : (31 - qb);       // long tile first
    const int q0 = qa*64 + wave*16;
    if (ph) __syncthreads();                  // full drain between phases

    bf16x8 qf[2];
    #pragma unroll
    for (int ks = 0; ks < 2; ++ks)
      qf[ks] = *reinterpret_cast<const bf16x8*>(
          &qkv[(tokbase + q0 + r)*3072 + h*64 + ks*32 + g*8]);

    f32x4 acc_o[4] = {};
    f32x4 acc_l = {};
    const int nkv = qa + 1;

    STAGE(0, 0);
    int cur = 0;
    for (int kb = 0; kb < nkv; ++kb) {
      __builtin_amdgcn_s_barrier();          // WAR gate: all waves done reading buf cur^1
      if (kb + 1 < nkv) {
        STAGE(cur ^ 1, kb + 1);              // issue next tile's 4 loads
        asm volatile("s_waitcnt vmcnt(4)" ::: "memory");  // cur tile landed; next in flight
      } else {
        asm volatile("s_waitcnt vmcnt(0)" ::: "memory");
      }
      __builtin_amdgcn_s_barrier();          // all waves' cur-tile loads landed
      const int kv0 = kb*64;
      const bool diag = (kb == qa);
      const int cb = (r & 7) << 3;           // read-side swizzle (u16 units)

      // S = Q K^T : 16q x 64kv per wave (log2-domain logits)
      f32x4 s[4] = {};
      #pragma unroll
      for (int nb = 0; nb < 4; ++nb) {
        #pragma unroll
        for (int ks = 0; ks < 2; ++ks) {
          bf16x8 kf = *reinterpret_cast<const bf16x8*>(
              &Klds[cur][(nb*16 + r)*64 + ((ks*32 + g*8) ^ cb)]);
          s[nb] = __builtin_amdgcn_mfma_f32_16x16x32_bf16(qf[ks], kf, s[nb], 0, 0, 0);
        }
      }
      // P = exp2(S); causal zero-mask on diagonal tile only
      #pragma unroll
      for (int i = 0; i < 4; ++i) {
        const int prow = g*4 + i;
        const int pcb = (prow & 7) << 3;
        #pragma unroll
        for (int nb = 0; nb < 4; ++nb) {
          float pv = __builtin_amdgcn_exp2f(s[nb][i]);
          if (diag && (kv0 + nb*16 + r > q0 + prow)) pv = 0.f;
          const bf16 bv = (bf16)pv;          // native RNE cvt
          P[wave][prow*64 + ((nb*16 + r) ^ pcb)] = __builtin_bit_cast(u16, bv);
        }
      }
      // O += P * V ; row-sum l += P * ones
      #pragma unroll
      for (int ks = 0; ks < 2; ++ks) {
        bf16x8 pf = *reinterpret_cast<const bf16x8*>(
            &P[wave][r*64 + ((ks*32 + g*8) ^ cb)]);
        acc_l = __builtin_amdgcn_mfma_f32_16x16x32_bf16(pf, ones, acc_l, 0, 0, 0);
        #pragma unroll
        for (int nt = 0; nt < 4; ++nt) {
          bf16x8 vf = *reinterpret_cast<const bf16x8*>(
              &Vlds[cur][(nt*16 + r)*64 + ((ks*32 + g*8) ^ cb)]);
          acc_o[nt] = __builtin_amdgcn_mfma_f32_16x16x32_bf16(pf, vf, acc_o[nt], 0, 0, 0);
        }
      }
      cur ^= 1;
    }
    #pragma unroll
    for (int i = 0; i < 4; ++i) {
      const float inv = 1.0f / acc_l[i];
      const size_t rowo = (tokbase + q0 + g*4 + i) * 1024;
      #pragma unroll
      for (int nt = 0; nt < 4; ++nt) {
        const bf16 bv = (bf16)(acc_o[nt][i] * inv);
        o[rowo + h*64 + nt*16 + r] = __builtin_bit_cast(u16, bv);
      }
    }
  }
}

extern "C" void kernel_launch(void* const* d_in, const int* in_sizes, int n_in,
                              void* d_out, int out_size, void* d_ws, size_t ws_size,
                              hipStream_t stream)
{
  const float* x      = (const float*)d_in[0];
  const float* wq     = (const float*)d_in[1];
  const float* wk     = (const float*)d_in[2];
  const float* wv     = (const float*)d_in[3];
  const float* w_proj = (const float*)d_in[4];
  const float* b_proj = (const float*)d_in[5];
  const float* w_ff1  = (const float*)d_in[6];
  const float* b_ff1  = (const float*)d_in[7];
  const float* w_ff2  = (const float*)d_in[8];
  const float* b_ff2  = (const float*)d_in[9];
  const float* ln1_g  = (const float*)d_in[10];
  const float* ln1_b  = (const float*)d_in[11];
  const float* ln2_g  = (const float*)d_in[12];
  const float* ln2_b  = (const float*)d_in[13];

  const int T = 2048;
  const int NT = 4096;   // B*T

  char* ws = (char*)d_ws;
  u16* Wbuf   = (u16*)(ws);                       // weight^T buffer, up to 8 MB
  u16* hbuf   = (u16*)(ws + ((size_t)8  << 20));  // LN output, 8 MB
  u16* qkvbuf = (u16*)(ws + ((size_t)16 << 20));  // 24 MB
  u16* obuf   = (u16*)(ws + ((size_t)40 << 20));  // 8 MB
  u16* ff1buf = qkvbuf;                           // 32 MB spans qkv+o region
  u16* vtbuf  = Wbuf;                             // aliased: lifetime disjoint from Wbuf uses
  float* x1   = (float*)d_out;                    // post-attn residual lives in d_out

  // LN1
  ln_kernel<false><<<dim3(NT), dim3(256), 0, stream>>>(x, ln1_g, ln1_b, hbuf, nullptr, nullptr);
  // W_qkv^T (per-head transpose [1024][64] -> [64][1024], 16 heads each)
  transpose_cast<<<dim3(2, 32, 16), dim3(32, 8), 0, stream>>>(wq, Wbuf + 0*1024*1024, 1024, 64);
  transpose_cast<<<dim3(2, 32, 16), dim3(32, 8), 0, stream>>>(wk, Wbuf + 1*1024*1024, 1024, 64);
  transpose_cast<<<dim3(2, 32, 16), dim3(32, 8), 0, stream>>>(wv, Wbuf + 2*1024*1024, 1024, 64);
  // QKV projection - 256x192 pipeline, full 256-block grid
  gemm_qkv<<<dim3(16, 16), dim3(512), 0, stream>>>(hbuf, Wbuf, NT, 3072, 1024, qkvbuf);
  // V^T for attention (after QKV gemm has finished reading Wbuf)
  vt_kernel<<<dim3(64, 2, 32), dim3(32, 8), 0, stream>>>(qkvbuf, vtbuf, T);
  // attention (uniform-work paired q-tiles, counted-vmcnt pipeline)
  attn_kernel<<<dim3(512), dim3(256), 0, stream>>>(qkvbuf, vtbuf, obuf, T);
  // output projection + bias + residual -> x1 (in d_out)
  transpose_cast<<<dim3(32, 32, 1), dim3(32, 8), 0, stream>>>(w_proj, Wbuf, 1024, 1024);
  gemm_128<<<dim3(8, 32), dim3(512), 0, stream>>>(obuf, Wbuf, NT, 1024, 1024, b_proj, x, x1);
  // LN2 (+ prefill x1 += b_ff2 for FF2's atomic split-K)
  ln_kernel<true><<<dim3(NT), dim3(256), 0, stream>>>(x1, ln2_g, ln2_b, hbuf, b_ff2, x1);
  // FF1 + bias + relu - 256^2 pipeline
  transpose_cast<<<dim3(128, 32, 1), dim3(32, 8), 0, stream>>>(w_ff1, Wbuf, 1024, 4096);
  gemm_bt8<2><<<dim3(16, 16), dim3(512), 0, stream>>>(hbuf, Wbuf, NT, 4096, 1024, b_ff1, ff1buf);
  // FF2: 128^2 split-K=2 (8-wave), atomic into prefilled x1 (d_out)
  transpose_cast<<<dim3(32, 128, 1), dim3(32, 8), 0, stream>>>(w_ff2, Wbuf, 4096, 1024);
  gemm_128_sk<<<dim3(512), dim3(512), 0, stream>>>(ff1buf, Wbuf, NT, 1024, 4096, (float*)d_out);
}